// Round 1
// baseline (969.696 us; speedup 1.0000x reference)
//
#include <hip/hip_runtime.h>
#include <math.h>

// MHA fp32 baseline: qkv-proj GEMM -> flash attention -> out-proj GEMM.
// All fp32 vector ALU (no MFMA yet) — correctness anchor for later bf16-MFMA rounds.
//
// ws layout (floats): q[2*16*2048*64] | k[same] | v[same] | attn[4096*1024]  = 64 MB total.

namespace {

constexpr int kHID = 1024;
constexpr int kNH  = 16;
constexpr int kHD  = 64;
constexpr int kSEQ = 2048;
constexpr int kB   = 2;

__device__ __forceinline__ float4 ld4(const float* p) { return *reinterpret_cast<const float4*>(p); }
__device__ __forceinline__ void st4(float* p, float4 v) { *reinterpret_cast<float4*>(p) = v; }

// ---------------------------------------------------------------------------
// QKV projection: X[4096,1024] @ W[1024,1024] + b -> out in [B,NH,SEQ,HD].
// 64x64 tile, K-step 16, 256 threads, 4x4 per thread. blockIdx.x == head.
// ---------------------------------------------------------------------------
__global__ __launch_bounds__(256, 2) void qkv_gemm_kernel(
    const float* __restrict__ X,
    const float* __restrict__ Wq, const float* __restrict__ Wk, const float* __restrict__ Wv,
    const float* __restrict__ bq, const float* __restrict__ bk, const float* __restrict__ bv,
    float* __restrict__ Qo, float* __restrict__ Ko, float* __restrict__ Vo)
{
    const float* W; const float* bias; float* out;
    if (blockIdx.z == 0)      { W = Wq; bias = bq; out = Qo; }
    else if (blockIdx.z == 1) { W = Wk; bias = bk; out = Ko; }
    else                      { W = Wv; bias = bv; out = Vo; }

    // As[k][m]: stride 68 (16B-aligned rows, odd mod-32 bank pattern for stores)
    __shared__ __align__(16) float As[16][68];
    __shared__ __align__(16) float Bs[16][64];

    const int tid = threadIdx.x;
    const int ti = tid >> 4, tj = tid & 15;
    const int rowBase = blockIdx.y * 64;
    const int h = blockIdx.x;  // column block == head (TN == HD == 64)

    float acc[4][4] = {};

    for (int k0 = 0; k0 < kHID; k0 += 16) {
        {   // A tile: 64 rows x 16 k. thread t: row t>>2, 4 k starting (t&3)*4
            const int m = tid >> 2, kq = (tid & 3) * 4;
            const float4 xv = ld4(&X[(size_t)(rowBase + m) * kHID + k0 + kq]);
            As[kq + 0][m] = xv.x; As[kq + 1][m] = xv.y;
            As[kq + 2][m] = xv.z; As[kq + 3][m] = xv.w;
        }
        {   // B tile: 16 k x 64 n
            const int kk = tid >> 4, nq = (tid & 15) * 4;
            st4(&Bs[kk][nq], ld4(&W[(size_t)(k0 + kk) * kHID + h * kHD + nq]));
        }
        __syncthreads();
        #pragma unroll
        for (int kk = 0; kk < 16; ++kk) {
            const float4 av = ld4(&As[kk][ti * 4]);   // 4 rows of A (contiguous in As)
            const float4 bv = ld4(&Bs[kk][tj * 4]);   // 4 cols of B
            const float* a = reinterpret_cast<const float*>(&av);
            const float* b = reinterpret_cast<const float*>(&bv);
            #pragma unroll
            for (int r = 0; r < 4; ++r)
                #pragma unroll
                for (int c = 0; c < 4; ++c)
                    acc[r][c] = fmaf(a[r], b[c], acc[r][c]);
        }
        __syncthreads();
    }

    const float4 bb = ld4(&bias[h * kHD + tj * 4]);
    const float* bbp = reinterpret_cast<const float*>(&bb);
    #pragma unroll
    for (int r = 0; r < 4; ++r) {
        const int m = rowBase + ti * 4 + r;
        const int bi = m >> 11;            // m / SEQ
        const int s  = m & (kSEQ - 1);
        float4 o;
        o.x = acc[r][0] + bbp[0]; o.y = acc[r][1] + bbp[1];
        o.z = acc[r][2] + bbp[2]; o.w = acc[r][3] + bbp[3];
        st4(&out[(((size_t)bi * kNH + h) * kSEQ + s) * kHD + tj * 4], o);
    }
}

// ---------------------------------------------------------------------------
// Output projection: A[4096,1024] @ Wo + bo -> out[4096,1024] (row-major)
// ---------------------------------------------------------------------------
__global__ __launch_bounds__(256, 2) void out_gemm_kernel(
    const float* __restrict__ A, const float* __restrict__ W,
    const float* __restrict__ bias, float* __restrict__ out)
{
    __shared__ __align__(16) float As[16][68];
    __shared__ __align__(16) float Bs[16][64];

    const int tid = threadIdx.x;
    const int ti = tid >> 4, tj = tid & 15;
    const int rowBase = blockIdx.y * 64;
    const int colBase = blockIdx.x * 64;

    float acc[4][4] = {};

    for (int k0 = 0; k0 < kHID; k0 += 16) {
        {
            const int m = tid >> 2, kq = (tid & 3) * 4;
            const float4 xv = ld4(&A[(size_t)(rowBase + m) * kHID + k0 + kq]);
            As[kq + 0][m] = xv.x; As[kq + 1][m] = xv.y;
            As[kq + 2][m] = xv.z; As[kq + 3][m] = xv.w;
        }
        {
            const int kk = tid >> 4, nq = (tid & 15) * 4;
            st4(&Bs[kk][nq], ld4(&W[(size_t)(k0 + kk) * kHID + colBase + nq]));
        }
        __syncthreads();
        #pragma unroll
        for (int kk = 0; kk < 16; ++kk) {
            const float4 av = ld4(&As[kk][ti * 4]);
            const float4 bv = ld4(&Bs[kk][tj * 4]);
            const float* a = reinterpret_cast<const float*>(&av);
            const float* b = reinterpret_cast<const float*>(&bv);
            #pragma unroll
            for (int r = 0; r < 4; ++r)
                #pragma unroll
                for (int c = 0; c < 4; ++c)
                    acc[r][c] = fmaf(a[r], b[c], acc[r][c]);
        }
        __syncthreads();
    }

    const float4 bb = ld4(&bias[colBase + tj * 4]);
    const float* bbp = reinterpret_cast<const float*>(&bb);
    #pragma unroll
    for (int r = 0; r < 4; ++r) {
        const int m = rowBase + ti * 4 + r;
        float4 o;
        o.x = acc[r][0] + bbp[0]; o.y = acc[r][1] + bbp[1];
        o.z = acc[r][2] + bbp[2]; o.w = acc[r][3] + bbp[3];
        st4(&out[(size_t)m * kHID + colBase + tj * 4], o);
    }
}

// ---------------------------------------------------------------------------
// Flash attention, fp32. One block = one (b, h, 64-row Q tile). 256 threads.
// K stored TRANSPOSED in LDS (Kt[d][kv], stride 68) so score-phase b128 reads
// are bank-conflict-free; P overlays the Kt buffer after a barrier.
// Output written straight into [B,S,HID] layout for the final projection.
// ---------------------------------------------------------------------------
__global__ __launch_bounds__(256, 2) void flash_kernel(
    const float* __restrict__ Qp, const float* __restrict__ Kp,
    const float* __restrict__ Vp, float* __restrict__ O)
{
    constexpr int LDT = 68;                   // row stride (floats), 16B-aligned
    __shared__ __align__(16) float Qs [64][LDT];
    __shared__ __align__(16) float KtP[64][LDT];  // K^T tile, then P tile
    __shared__ __align__(16) float Vs [64][LDT];

    const int tid = threadIdx.x;
    const int ti = tid >> 4, tj = tid & 15;
    const int q0 = blockIdx.x * 64;
    const int h  = blockIdx.y;
    const int bz = blockIdx.z;
    const size_t headBase = ((size_t)bz * kNH + h) * (size_t)kSEQ * kHD;

    // ---- load Q tile (scaled by 1/sqrt(D)) ----
    {
        const int m = tid >> 2, d0 = (tid & 3) * 16;
        const float* src = &Qp[headBase + (size_t)(q0 + m) * kHD + d0];
        #pragma unroll
        for (int i = 0; i < 16; i += 4) {
            float4 qv = ld4(src + i);
            qv.x *= 0.125f; qv.y *= 0.125f; qv.z *= 0.125f; qv.w *= 0.125f;
            st4(&Qs[m][d0 + i], qv);
        }
    }

    float acc[4][4] = {};
    float mi[4] = {-INFINITY, -INFINITY, -INFINITY, -INFINITY};
    float li[4] = {0.f, 0.f, 0.f, 0.f};
    float* Pbuf = &KtP[0][0];

    for (int kv0 = 0; kv0 < kSEQ; kv0 += 64) {
        // ---- load K (transposed) and V tiles ----
        {
            const int m = tid >> 2, d0 = (tid & 3) * 16;
            const float* ksrc = &Kp[headBase + (size_t)(kv0 + m) * kHD + d0];
            const float* vsrc = &Vp[headBase + (size_t)(kv0 + m) * kHD + d0];
            #pragma unroll
            for (int i = 0; i < 16; i += 4) {
                const float4 kv = ld4(ksrc + i);
                KtP[d0 + i + 0][m] = kv.x;
                KtP[d0 + i + 1][m] = kv.y;
                KtP[d0 + i + 2][m] = kv.z;
                KtP[d0 + i + 3][m] = kv.w;
                st4(&Vs[m][d0 + i], ld4(vsrc + i));
            }
        }
        __syncthreads();

        // ---- scores: sc[r][c] = sum_d Qs[qr][d] * K[kc][d]  (K^T layout) ----
        float sc[4][4] = {};
        for (int d = 0; d < kHD; d += 4) {
            float4 qv[4], kt[4];
            #pragma unroll
            for (int r = 0; r < 4; ++r) qv[r] = ld4(&Qs[ti * 4 + r][d]);
            #pragma unroll
            for (int dd = 0; dd < 4; ++dd) kt[dd] = ld4(&KtP[d + dd][tj * 4]);
            #pragma unroll
            for (int r = 0; r < 4; ++r) {
                const float* q = reinterpret_cast<const float*>(&qv[r]);
                #pragma unroll
                for (int dd = 0; dd < 4; ++dd) {
                    const float* k = reinterpret_cast<const float*>(&kt[dd]);
                    #pragma unroll
                    for (int c = 0; c < 4; ++c)
                        sc[r][c] = fmaf(q[dd], k[c], sc[r][c]);
                }
            }
        }
        __syncthreads();  // all K reads done before P overlays the buffer

        // ---- online softmax (row reduction over the 16-lane tj group) ----
        float pr[4][4], fac[4];
        #pragma unroll
        for (int r = 0; r < 4; ++r) {
            float rm = fmaxf(fmaxf(sc[r][0], sc[r][1]), fmaxf(sc[r][2], sc[r][3]));
            #pragma unroll
            for (int msk = 1; msk < 16; msk <<= 1)
                rm = fmaxf(rm, __shfl_xor(rm, msk));
            const float mn = fmaxf(mi[r], rm);
            fac[r] = __expf(mi[r] - mn);
            mi[r] = mn;
            float rs = 0.f;
            #pragma unroll
            for (int c = 0; c < 4; ++c) { pr[r][c] = __expf(sc[r][c] - mn); rs += pr[r][c]; }
            #pragma unroll
            for (int msk = 1; msk < 16; msk <<= 1)
                rs += __shfl_xor(rs, msk);
            li[r] = li[r] * fac[r] + rs;
        }
        // write P, rescale accumulator
        #pragma unroll
        for (int r = 0; r < 4; ++r) {
            float4 p4; p4.x = pr[r][0]; p4.y = pr[r][1]; p4.z = pr[r][2]; p4.w = pr[r][3];
            st4(&Pbuf[(size_t)(ti * 4 + r) * LDT + tj * 4], p4);
            #pragma unroll
            for (int c = 0; c < 4; ++c) acc[r][c] *= fac[r];
        }
        __syncthreads();

        // ---- PV: acc[r][d] += sum_kv P[qr][kv] * V[kv][d] ----
        for (int kv = 0; kv < 64; kv += 4) {
            float4 pv[4], vv[4];
            #pragma unroll
            for (int r = 0; r < 4; ++r) pv[r] = ld4(&Pbuf[(size_t)(ti * 4 + r) * LDT + kv]);
            #pragma unroll
            for (int j = 0; j < 4; ++j) vv[j] = ld4(&Vs[kv + j][tj * 4]);
            #pragma unroll
            for (int r = 0; r < 4; ++r) {
                const float* p = reinterpret_cast<const float*>(&pv[r]);
                #pragma unroll
                for (int j = 0; j < 4; ++j) {
                    const float* v = reinterpret_cast<const float*>(&vv[j]);
                    #pragma unroll
                    for (int c = 0; c < 4; ++c)
                        acc[r][c] = fmaf(p[j], v[c], acc[r][c]);
                }
            }
        }
        __syncthreads();  // before next tile overwrites KtP/Vs
    }

    // ---- epilogue: normalize, write [B,S,HID] ----
    #pragma unroll
    for (int r = 0; r < 4; ++r) {
        const float inv = 1.0f / li[r];
        const int s = q0 + ti * 4 + r;
        float4 o;
        o.x = acc[r][0] * inv; o.y = acc[r][1] * inv;
        o.z = acc[r][2] * inv; o.w = acc[r][3] * inv;
        st4(&O[((size_t)bz * kSEQ + s) * kHID + h * kHD + tj * 4], o);
    }
}

}  // namespace

extern "C" void kernel_launch(void* const* d_in, const int* in_sizes, int n_in,
                              void* d_out, int out_size, void* d_ws, size_t ws_size,
                              hipStream_t stream) {
    (void)in_sizes; (void)n_in; (void)out_size;
    const float* x  = (const float*)d_in[0];
    const float* Wq = (const float*)d_in[1];
    const float* bq = (const float*)d_in[2];
    const float* Wk = (const float*)d_in[3];
    const float* bk = (const float*)d_in[4];
    const float* Wv = (const float*)d_in[5];
    const float* bv = (const float*)d_in[6];
    const float* Wo = (const float*)d_in[7];
    const float* bo = (const float*)d_in[8];

    constexpr size_t kHeadElems = (size_t)kB * kNH * kSEQ * kHD;  // 4 Mi floats
    if (ws_size < 4 * kHeadElems * sizeof(float)) return;  // need 64 MB scratch

    float* q    = (float*)d_ws;
    float* k    = q + kHeadElems;
    float* v    = k + kHeadElems;
    float* attn = v + kHeadElems;

    // 1) QKV projections (one launch, z selects q/k/v)
    qkv_gemm_kernel<<<dim3(kHID / 64, (kB * kSEQ) / 64, 3), 256, 0, stream>>>(
        x, Wq, Wk, Wv, bq, bk, bv, q, k, v);

    // 2) flash attention -> attn in [B,S,HID]
    flash_kernel<<<dim3(kSEQ / 64, kNH, kB), 256, 0, stream>>>(q, k, v, attn);

    // 3) output projection -> d_out
    out_gemm_kernel<<<dim3(kHID / 64, (kB * kSEQ) / 64), 256, 0, stream>>>(
        attn, Wo, bo, (float*)d_out);
}

// Round 2
// 230.286 us; speedup vs baseline: 4.2108x; 4.2108x over previous
//
#include <hip/hip_runtime.h>
#include <math.h>

// bf16-MFMA MHA: cvt/transpose pre-pass -> qkv MFMA GEMM -> MFMA flash attn -> out MFMA GEMM.
// MFMA 16x16x32 bf16 layouts (HW-verified, learn_hip m89/m92):
//   A frag: lane holds A[l&15][8*(l>>4)+e], e=0..7 (k-contiguous bf16x8)
//   B frag: lane holds B[8*(l>>4)+e][l&15]
//   C/D:    lane reg r -> C[(l>>4)*4 + r][l&15]

namespace {

constexpr int kHID = 1024;
constexpr int kNH  = 16;
constexpr int kHD  = 64;
constexpr int kSEQ = 2048;

typedef unsigned short ushortT;
typedef __attribute__((ext_vector_type(8))) short   bf16x8;
typedef __attribute__((ext_vector_type(4))) float   f32x4;
typedef __attribute__((ext_vector_type(4))) unsigned short u16x4;

#define MFMA(a, b, c) __builtin_amdgcn_mfma_f32_16x16x32_bf16((a), (b), (c), 0, 0, 0)

typedef const __attribute__((address_space(1))) void GVoid;
typedef __attribute__((address_space(3))) void SVoid;

__device__ __forceinline__ void gload_lds16(const ushortT* g, ushortT* l) {
    __builtin_amdgcn_global_load_lds((GVoid*)g, (SVoid*)l, 16, 0, 0);
}

__device__ __forceinline__ ushortT f2bf(float f) {
    unsigned u = __builtin_bit_cast(unsigned, f);
    u += 0x7fffu + ((u >> 16) & 1u);
    return (ushortT)(u >> 16);
}

__device__ __forceinline__ float4 ld4f(const float* p) { return *reinterpret_cast<const float4*>(p); }

// ---------------------------------------------------------------------------
// x fp32 -> bf16
// ---------------------------------------------------------------------------
__global__ __launch_bounds__(256) void cvtx_kernel(const float* __restrict__ x,
                                                   ushortT* __restrict__ xb) {
    const size_t i = ((size_t)blockIdx.x * 256 + threadIdx.x) * 4;
    const float4 f = ld4f(&x[i]);
    u16x4 o = { f2bf(f.x), f2bf(f.y), f2bf(f.z), f2bf(f.w) };
    *reinterpret_cast<u16x4*>(&xb[i]) = o;
}

// ---------------------------------------------------------------------------
// W[k][n] fp32 -> Wt[n][k] bf16, 64x64 tiles via LDS. z selects matrix.
// ---------------------------------------------------------------------------
__global__ __launch_bounds__(256) void transw_kernel(
    const float* __restrict__ W0, const float* __restrict__ W1,
    const float* __restrict__ W2, const float* __restrict__ W3,
    ushortT* __restrict__ WtAll) {
    __shared__ ushortT T[64 * 72];
    const float* W = (blockIdx.z == 0) ? W0 : (blockIdx.z == 1) ? W1 : (blockIdx.z == 2) ? W2 : W3;
    ushortT* Wt = WtAll + (size_t)blockIdx.z * kHID * kHID;
    const int kb = blockIdx.y * 64, nb = blockIdx.x * 64;
    const int tid = threadIdx.x;
    {
        const int kr = tid >> 2, nc = (tid & 3) * 16;
        #pragma unroll
        for (int i = 0; i < 16; i += 4) {
            const float4 f = ld4f(&W[(size_t)(kb + kr) * kHID + nb + nc + i]);
            T[kr * 72 + nc + i + 0] = f2bf(f.x);
            T[kr * 72 + nc + i + 1] = f2bf(f.y);
            T[kr * 72 + nc + i + 2] = f2bf(f.z);
            T[kr * 72 + nc + i + 3] = f2bf(f.w);
        }
    }
    __syncthreads();
    {
        const int nr = tid >> 2, kc = (tid & 3) * 16;
        ushortT tmp[16];
        #pragma unroll
        for (int i = 0; i < 16; ++i) tmp[i] = T[(kc + i) * 72 + nr];
        *reinterpret_cast<bf16x8*>(&Wt[(size_t)(nb + nr) * kHID + kb + kc]) =
            *reinterpret_cast<bf16x8*>(&tmp[0]);
        *reinterpret_cast<bf16x8*>(&Wt[(size_t)(nb + nr) * kHID + kb + kc + 8]) =
            *reinterpret_cast<bf16x8*>(&tmp[8]);
    }
}

// ---------------------------------------------------------------------------
// QKV GEMM: xb[4096][1024] @ W (as Wt[n][k]) + bias, scaled, -> bf16 [B,H,S,D].
// 128x128 tile, BK=64, 4 waves each 64x64, global_load_lds w=16 (m97 recipe).
// blockIdx.z in {0,1,2} selects q/k/v.
// ---------------------------------------------------------------------------
__global__ __launch_bounds__(256) void qkv_mfma_gemm(
    const ushortT* __restrict__ A, const ushortT* __restrict__ WtAll,
    const float* __restrict__ bq, const float* __restrict__ bk, const float* __restrict__ bv,
    ushortT* __restrict__ qkvb) {
    __shared__ ushortT As[128 * 64];
    __shared__ ushortT Bs[128 * 64];

    const int z = blockIdx.z;
    const ushortT* Bt = WtAll + (size_t)z * kHID * kHID;
    const float* bias = (z == 0) ? bq : (z == 1) ? bk : bv;
    ushortT* out = qkvb + (size_t)z * 2 * kNH * kSEQ * kHD;
    const float scale = (z == 0) ? 0.125f : 1.0f;

    const int tid = threadIdx.x, wid = tid >> 6, lane = tid & 63;
    const int hi = lane >> 4, lo = lane & 15;
    const int rowBase = blockIdx.y * 128, colBase = blockIdx.x * 128;
    const int wr = wid >> 1, wc = wid & 1;

    const f32x4 z4 = {0.f, 0.f, 0.f, 0.f};
    f32x4 acc[4][4];
    #pragma unroll
    for (int mi = 0; mi < 4; ++mi)
        #pragma unroll
        for (int ni = 0; ni < 4; ++ni) acc[mi][ni] = z4;

    for (int k0 = 0; k0 < kHID; k0 += 64) {
        #pragma unroll
        for (int i = 0; i < 4; ++i) {
            const int chunk = wid * 4 + i;                 // wave-uniform
            const int row = chunk * 8 + (lane >> 3);
            const int c8 = (lane & 7) * 8;
            gload_lds16(&A [(size_t)(rowBase + row) * kHID + k0 + c8], &As[chunk * 512]);
            gload_lds16(&Bt[(size_t)(colBase + row) * kHID + k0 + c8], &Bs[chunk * 512]);
        }
        __syncthreads();
        #pragma unroll
        for (int ks = 0; ks < 2; ++ks) {
            bf16x8 af[4], bfr[4];
            #pragma unroll
            for (int mi = 0; mi < 4; ++mi)
                af[mi] = *reinterpret_cast<const bf16x8*>(&As[(64 * wr + 16 * mi + lo) * 64 + 32 * ks + 8 * hi]);
            #pragma unroll
            for (int ni = 0; ni < 4; ++ni)
                bfr[ni] = *reinterpret_cast<const bf16x8*>(&Bs[(64 * wc + 16 * ni + lo) * 64 + 32 * ks + 8 * hi]);
            #pragma unroll
            for (int mi = 0; mi < 4; ++mi)
                #pragma unroll
                for (int ni = 0; ni < 4; ++ni)
                    acc[mi][ni] = MFMA(af[mi], bfr[ni], acc[mi][ni]);
        }
        __syncthreads();
    }

    #pragma unroll
    for (int ni = 0; ni < 4; ++ni) {
        const int col = colBase + 64 * wc + 16 * ni + lo;
        const float bcol = bias[col];
        const int h = col >> 6, d = col & 63;
        #pragma unroll
        for (int mi = 0; mi < 4; ++mi)
            #pragma unroll
            for (int r = 0; r < 4; ++r) {
                const int m = rowBase + 64 * wr + 16 * mi + 4 * hi + r;
                const int b = m >> 11, s = m & (kSEQ - 1);
                out[(((size_t)b * kNH + h) * kSEQ + s) * kHD + d] =
                    f2bf((acc[mi][ni][r] + bcol) * scale);
            }
    }
}

// ---------------------------------------------------------------------------
// Output GEMM: attnb[4096][1024] bf16 @ Wo (as Wt) + bo -> fp32 d_out.
// ---------------------------------------------------------------------------
__global__ __launch_bounds__(256) void out_mfma_gemm(
    const ushortT* __restrict__ A, const ushortT* __restrict__ Bt,
    const float* __restrict__ bias, float* __restrict__ out) {
    __shared__ ushortT As[128 * 64];
    __shared__ ushortT Bs[128 * 64];

    const int tid = threadIdx.x, wid = tid >> 6, lane = tid & 63;
    const int hi = lane >> 4, lo = lane & 15;
    const int rowBase = blockIdx.y * 128, colBase = blockIdx.x * 128;
    const int wr = wid >> 1, wc = wid & 1;

    const f32x4 z4 = {0.f, 0.f, 0.f, 0.f};
    f32x4 acc[4][4];
    #pragma unroll
    for (int mi = 0; mi < 4; ++mi)
        #pragma unroll
        for (int ni = 0; ni < 4; ++ni) acc[mi][ni] = z4;

    for (int k0 = 0; k0 < kHID; k0 += 64) {
        #pragma unroll
        for (int i = 0; i < 4; ++i) {
            const int chunk = wid * 4 + i;
            const int row = chunk * 8 + (lane >> 3);
            const int c8 = (lane & 7) * 8;
            gload_lds16(&A [(size_t)(rowBase + row) * kHID + k0 + c8], &As[chunk * 512]);
            gload_lds16(&Bt[(size_t)(colBase + row) * kHID + k0 + c8], &Bs[chunk * 512]);
        }
        __syncthreads();
        #pragma unroll
        for (int ks = 0; ks < 2; ++ks) {
            bf16x8 af[4], bfr[4];
            #pragma unroll
            for (int mi = 0; mi < 4; ++mi)
                af[mi] = *reinterpret_cast<const bf16x8*>(&As[(64 * wr + 16 * mi + lo) * 64 + 32 * ks + 8 * hi]);
            #pragma unroll
            for (int ni = 0; ni < 4; ++ni)
                bfr[ni] = *reinterpret_cast<const bf16x8*>(&Bs[(64 * wc + 16 * ni + lo) * 64 + 32 * ks + 8 * hi]);
            #pragma unroll
            for (int mi = 0; mi < 4; ++mi)
                #pragma unroll
                for (int ni = 0; ni < 4; ++ni)
                    acc[mi][ni] = MFMA(af[mi], bfr[ni], acc[mi][ni]);
        }
        __syncthreads();
    }

    #pragma unroll
    for (int ni = 0; ni < 4; ++ni) {
        const int col = colBase + 64 * wc + 16 * ni + lo;
        const float bcol = bias[col];
        #pragma unroll
        for (int mi = 0; mi < 4; ++mi)
            #pragma unroll
            for (int r = 0; r < 4; ++r) {
                const int m = rowBase + 64 * wr + 16 * mi + 4 * hi + r;
                out[(size_t)m * kHID + col] = acc[mi][ni][r] + bcol;
            }
    }
}

// ---------------------------------------------------------------------------
// MFMA flash attention. Block = (b, h, 128-row Q tile), 4 waves x 32 q-rows.
// Q in registers (pre-scaled by 0.125 in qkv GEMM). K row-major + V transposed
// in XOR-swizzled LDS (elem ^= (row&7)<<3). P via per-wave swizzled LDS.
// Output bf16 [B,S,HID].
// ---------------------------------------------------------------------------
__global__ __launch_bounds__(256) void flash_mfma_kernel(
    const ushortT* __restrict__ Qb, const ushortT* __restrict__ Kb,
    const ushortT* __restrict__ Vb, ushortT* __restrict__ Ob) {
    __shared__ ushortT Ks [64 * 64];
    __shared__ ushortT Vts[64 * 64];
    __shared__ ushortT Ps [4 * 32 * 64];

    const int tid = threadIdx.x, wid = tid >> 6, lane = tid & 63;
    const int hi = lane >> 4, lo = lane & 15;
    const int q0 = blockIdx.x * 128;
    const size_t headBase = ((size_t)blockIdx.z * kNH + blockIdx.y) * (size_t)(kSEQ * kHD);

    // Q fragments: rows q0 + 32*wid + 16*rb + lo, k-chunk 32*c + 8*hi
    bf16x8 qf[2][2];
    #pragma unroll
    for (int rb = 0; rb < 2; ++rb)
        #pragma unroll
        for (int c = 0; c < 2; ++c)
            qf[rb][c] = *reinterpret_cast<const bf16x8*>(
                &Qb[headBase + (size_t)(q0 + 32 * wid + 16 * rb + lo) * kHD + 32 * c + 8 * hi]);

    const f32x4 z4 = {0.f, 0.f, 0.f, 0.f};
    f32x4 acc[2][4];
    #pragma unroll
    for (int rb = 0; rb < 2; ++rb)
        #pragma unroll
        for (int n = 0; n < 4; ++n) acc[rb][n] = z4;
    float m_[2][4], l_[2][4];
    #pragma unroll
    for (int rb = 0; rb < 2; ++rb)
        #pragma unroll
        for (int r = 0; r < 4; ++r) { m_[rb][r] = -INFINITY; l_[rb][r] = 0.f; }

    for (int kv0 = 0; kv0 < kSEQ; kv0 += 64) {
        // ---- stage K (row-major) and V (transposed), swizzled ----
        {
            const int rr = tid >> 3, c8 = (tid & 7) * 8;
            #pragma unroll
            for (int half = 0; half < 2; ++half) {
                const int row = rr + 32 * half;  // kv within tile
                const bf16x8 k8 = *reinterpret_cast<const bf16x8*>(
                    &Kb[headBase + (size_t)(kv0 + row) * kHD + c8]);
                *reinterpret_cast<bf16x8*>(&Ks[row * 64 + (c8 ^ ((row & 7) << 3))]) = k8;
                const bf16x8 v8 = *reinterpret_cast<const bf16x8*>(
                    &Vb[headBase + (size_t)(kv0 + row) * kHD + c8]);
                const short* vs = reinterpret_cast<const short*>(&v8);
                #pragma unroll
                for (int e = 0; e < 8; ++e) {
                    const int d = c8 + e;
                    Vts[d * 64 + (row ^ ((d & 7) << 3))] = (ushortT)vs[e];
                }
            }
        }
        __syncthreads();

        // ---- QK^T: sc[rb][f] reg r = S[32w+16rb+4hi+r][16f+lo] ----
        f32x4 sc[2][4];
        #pragma unroll
        for (int f = 0; f < 4; ++f) {
            const int krow = 16 * f + lo;
            const bf16x8 kf0 = *reinterpret_cast<const bf16x8*>(
                &Ks[krow * 64 + ((8 * hi) ^ ((krow & 7) << 3))]);
            const bf16x8 kf1 = *reinterpret_cast<const bf16x8*>(
                &Ks[krow * 64 + ((32 + 8 * hi) ^ ((krow & 7) << 3))]);
            #pragma unroll
            for (int rb = 0; rb < 2; ++rb) {
                f32x4 s = z4;
                s = MFMA(qf[rb][0], kf0, s);
                s = MFMA(qf[rb][1], kf1, s);
                sc[rb][f] = s;
            }
        }

        // ---- online softmax + P write (bf16, swizzled per-wave buffer) ----
        #pragma unroll
        for (int rb = 0; rb < 2; ++rb) {
            #pragma unroll
            for (int r = 0; r < 4; ++r) {
                const float v0 = sc[rb][0][r], v1 = sc[rb][1][r];
                const float v2 = sc[rb][2][r], v3 = sc[rb][3][r];
                float rm = fmaxf(fmaxf(v0, v1), fmaxf(v2, v3));
                #pragma unroll
                for (int msk = 1; msk < 16; msk <<= 1) rm = fmaxf(rm, __shfl_xor(rm, msk));
                const float mn = fmaxf(m_[rb][r], rm);
                const float fac = __expf(m_[rb][r] - mn);
                m_[rb][r] = mn;
                const float p0 = __expf(v0 - mn), p1 = __expf(v1 - mn);
                const float p2 = __expf(v2 - mn), p3 = __expf(v3 - mn);
                float rs = p0 + p1 + p2 + p3;
                #pragma unroll
                for (int msk = 1; msk < 16; msk <<= 1) rs += __shfl_xor(rs, msk);
                l_[rb][r] = l_[rb][r] * fac + rs;
                #pragma unroll
                for (int n = 0; n < 4; ++n) acc[rb][n][r] *= fac;
                const int prow = 16 * rb + 4 * hi + r;
                const int swz = (prow & 7) << 3;
                ushortT* pbase = &Ps[wid * 2048 + prow * 64];
                pbase[(lo +  0) ^ swz] = f2bf(p0);
                pbase[(lo + 16) ^ swz] = f2bf(p1);
                pbase[(lo + 32) ^ swz] = f2bf(p2);
                pbase[(lo + 48) ^ swz] = f2bf(p3);
            }
        }

        // ---- PV: acc[rb][n] += P[16rb..+16][kv-chunk] x V[kv-chunk][16n..+16] ----
        #pragma unroll
        for (int c = 0; c < 2; ++c) {
            bf16x8 pa[2];
            #pragma unroll
            for (int rb = 0; rb < 2; ++rb) {
                const int prow = 16 * rb + lo;
                pa[rb] = *reinterpret_cast<const bf16x8*>(
                    &Ps[wid * 2048 + prow * 64 + ((32 * c + 8 * hi) ^ ((prow & 7) << 3))]);
            }
            #pragma unroll
            for (int n = 0; n < 4; ++n) {
                const int vrow = 16 * n + lo;
                const bf16x8 vf = *reinterpret_cast<const bf16x8*>(
                    &Vts[vrow * 64 + ((32 * c + 8 * hi) ^ ((vrow & 7) << 3))]);
                acc[0][n] = MFMA(pa[0], vf, acc[0][n]);
                acc[1][n] = MFMA(pa[1], vf, acc[1][n]);
            }
        }
        __syncthreads();
    }

    // ---- epilogue: normalize, write bf16 [B,S,HID] ----
    #pragma unroll
    for (int rb = 0; rb < 2; ++rb)
        #pragma unroll
        for (int r = 0; r < 4; ++r) {
            const float inv = 1.0f / l_[rb][r];
            const int s = q0 + 32 * wid + 16 * rb + 4 * hi + r;
            const size_t base = ((size_t)blockIdx.z * kSEQ + s) * kHID + (size_t)blockIdx.y * kHD;
            #pragma unroll
            for (int n = 0; n < 4; ++n)
                Ob[base + 16 * n + lo] = f2bf(acc[rb][n][r] * inv);
        }
}

}  // namespace

extern "C" void kernel_launch(void* const* d_in, const int* in_sizes, int n_in,
                              void* d_out, int out_size, void* d_ws, size_t ws_size,
                              hipStream_t stream) {
    (void)in_sizes; (void)n_in; (void)out_size;
    const float* x  = (const float*)d_in[0];
    const float* Wq = (const float*)d_in[1];
    const float* bq = (const float*)d_in[2];
    const float* Wk = (const float*)d_in[3];
    const float* bk = (const float*)d_in[4];
    const float* Wv = (const float*)d_in[5];
    const float* bv = (const float*)d_in[6];
    const float* Wo = (const float*)d_in[7];
    const float* bo = (const float*)d_in[8];

    constexpr size_t kTok   = (size_t)2 * kSEQ;          // 4096
    constexpr size_t kXE    = kTok * kHID;               // 4 Mi elems
    constexpr size_t kWE    = (size_t)kHID * kHID;       // 1 Mi elems
    // ws (ushort units): xb[kXE] | WtAll[4*kWE] | qkvb[3*kXE] | attnb[kXE]
    const size_t needed = (kXE + 4 * kWE + 3 * kXE + kXE) * sizeof(ushortT);
    if (ws_size < needed) return;

    ushortT* xb    = (ushortT*)d_ws;
    ushortT* WtAll = xb + kXE;
    ushortT* qkvb  = WtAll + 4 * kWE;
    ushortT* attnb = qkvb + 3 * kXE;

    const ushortT* qb = qkvb;
    const ushortT* kb = qkvb + kXE;
    const ushortT* vb = qkvb + 2 * kXE;

    cvtx_kernel<<<dim3((unsigned)(kXE / (256 * 4))), 256, 0, stream>>>(x, xb);
    transw_kernel<<<dim3(16, 16, 4), 256, 0, stream>>>(Wq, Wk, Wv, Wo, WtAll);

    qkv_mfma_gemm<<<dim3(8, 32, 3), 256, 0, stream>>>(xb, WtAll, bq, bk, bv, qkvb);

    flash_mfma_kernel<<<dim3(kSEQ / 128, kNH, 2), 256, 0, stream>>>(qb, kb, vb, attnb);

    out_mfma_gemm<<<dim3(8, 32), 256, 0, stream>>>(attnb, WtAll + 3 * kWE, bo, (float*)d_out);
}

// Round 3
// 202.167 us; speedup vs baseline: 4.7965x; 1.1391x over previous
//
#include <hip/hip_runtime.h>
#include <math.h>

// bf16-MFMA MHA v3: cvt/transpose pre-pass -> qkv MFMA GEMM (V written transposed)
// -> dbuf async-staged MFMA flash attn -> out MFMA GEMM.
// MFMA 16x16x32 bf16 layouts (HW-verified, learn_hip m89/m92):
//   A frag: lane holds A[l&15][8*(l>>4)+e], e=0..7 (k-contiguous bf16x8)
//   B frag: lane holds B[8*(l>>4)+e][l&15]
//   C/D:    lane reg r -> C[(l>>4)*4 + r][l&15]

namespace {

constexpr int kHID = 1024;
constexpr int kNH  = 16;
constexpr int kHD  = 64;
constexpr int kSEQ = 2048;

// 1/sqrt(64) * log2(e): scores computed directly in log2 domain -> exp2f in softmax.
constexpr float kQScale = 0.125f * 1.4426950408889634f;

typedef unsigned short ushortT;
typedef __attribute__((ext_vector_type(8))) short   bf16x8;
typedef __attribute__((ext_vector_type(4))) float   f32x4;
typedef __attribute__((ext_vector_type(4))) unsigned short u16x4;

#define MFMA(a, b, c) __builtin_amdgcn_mfma_f32_16x16x32_bf16((a), (b), (c), 0, 0, 0)

typedef const __attribute__((address_space(1))) void GVoid;
typedef __attribute__((address_space(3))) void SVoid;

__device__ __forceinline__ void gload_lds16(const ushortT* g, ushortT* l) {
    __builtin_amdgcn_global_load_lds((GVoid*)g, (SVoid*)l, 16, 0, 0);
}

__device__ __forceinline__ ushortT f2bf(float f) {
    unsigned u = __builtin_bit_cast(unsigned, f);
    u += 0x7fffu + ((u >> 16) & 1u);
    return (ushortT)(u >> 16);
}

__device__ __forceinline__ float4 ld4f(const float* p) { return *reinterpret_cast<const float4*>(p); }

// ---------------------------------------------------------------------------
// x fp32 -> bf16
// ---------------------------------------------------------------------------
__global__ __launch_bounds__(256) void cvtx_kernel(const float* __restrict__ x,
                                                   ushortT* __restrict__ xb) {
    const size_t i = ((size_t)blockIdx.x * 256 + threadIdx.x) * 4;
    const float4 f = ld4f(&x[i]);
    u16x4 o = { f2bf(f.x), f2bf(f.y), f2bf(f.z), f2bf(f.w) };
    *reinterpret_cast<u16x4*>(&xb[i]) = o;
}

// ---------------------------------------------------------------------------
// W[k][n] fp32 -> Wt[n][k] bf16, 64x64 tiles via LDS. z selects matrix.
// ---------------------------------------------------------------------------
__global__ __launch_bounds__(256) void transw_kernel(
    const float* __restrict__ W0, const float* __restrict__ W1,
    const float* __restrict__ W2, const float* __restrict__ W3,
    ushortT* __restrict__ WtAll) {
    __shared__ ushortT T[64 * 72];
    const float* W = (blockIdx.z == 0) ? W0 : (blockIdx.z == 1) ? W1 : (blockIdx.z == 2) ? W2 : W3;
    ushortT* Wt = WtAll + (size_t)blockIdx.z * kHID * kHID;
    const int kb = blockIdx.y * 64, nb = blockIdx.x * 64;
    const int tid = threadIdx.x;
    {
        const int kr = tid >> 2, nc = (tid & 3) * 16;
        #pragma unroll
        for (int i = 0; i < 16; i += 4) {
            const float4 f = ld4f(&W[(size_t)(kb + kr) * kHID + nb + nc + i]);
            T[kr * 72 + nc + i + 0] = f2bf(f.x);
            T[kr * 72 + nc + i + 1] = f2bf(f.y);
            T[kr * 72 + nc + i + 2] = f2bf(f.z);
            T[kr * 72 + nc + i + 3] = f2bf(f.w);
        }
    }
    __syncthreads();
    {
        const int nr = tid >> 2, kc = (tid & 3) * 16;
        ushortT tmp[16];
        #pragma unroll
        for (int i = 0; i < 16; ++i) tmp[i] = T[(kc + i) * 72 + nr];
        *reinterpret_cast<bf16x8*>(&Wt[(size_t)(nb + nr) * kHID + kb + kc]) =
            *reinterpret_cast<bf16x8*>(&tmp[0]);
        *reinterpret_cast<bf16x8*>(&Wt[(size_t)(nb + nr) * kHID + kb + kc + 8]) =
            *reinterpret_cast<bf16x8*>(&tmp[8]);
    }
}

// ---------------------------------------------------------------------------
// QKV GEMM: xb[4096][1024] @ W (as Wt[n][k]) + bias -> bf16.
// Q (z==0): [B,H,S,D] scaled by kQScale.  K (z==1): [B,H,S,D].
// V (z==2): TRANSPOSED [B,H,D,S] so flash stages V^T with plain vector copies.
// ---------------------------------------------------------------------------
__global__ __launch_bounds__(256) void qkv_mfma_gemm(
    const ushortT* __restrict__ A, const ushortT* __restrict__ WtAll,
    const float* __restrict__ bq, const float* __restrict__ bk, const float* __restrict__ bv,
    ushortT* __restrict__ qkvb) {
    __shared__ ushortT As[128 * 64];
    __shared__ ushortT Bs[128 * 64];

    const int z = blockIdx.z;
    const ushortT* Bt = WtAll + (size_t)z * kHID * kHID;
    const float* bias = (z == 0) ? bq : (z == 1) ? bk : bv;
    ushortT* out = qkvb + (size_t)z * 2 * kNH * kSEQ * kHD;
    const float scale = (z == 0) ? kQScale : 1.0f;

    const int tid = threadIdx.x, wid = tid >> 6, lane = tid & 63;
    const int hi = lane >> 4, lo = lane & 15;
    const int rowBase = blockIdx.y * 128, colBase = blockIdx.x * 128;
    const int wr = wid >> 1, wc = wid & 1;

    const f32x4 z4 = {0.f, 0.f, 0.f, 0.f};
    f32x4 acc[4][4];
    #pragma unroll
    for (int mi = 0; mi < 4; ++mi)
        #pragma unroll
        for (int ni = 0; ni < 4; ++ni) acc[mi][ni] = z4;

    for (int k0 = 0; k0 < kHID; k0 += 64) {
        #pragma unroll
        for (int i = 0; i < 4; ++i) {
            const int chunk = wid * 4 + i;                 // wave-uniform
            const int row = chunk * 8 + (lane >> 3);
            const int c8 = (lane & 7) * 8;
            gload_lds16(&A [(size_t)(rowBase + row) * kHID + k0 + c8], &As[chunk * 512]);
            gload_lds16(&Bt[(size_t)(colBase + row) * kHID + k0 + c8], &Bs[chunk * 512]);
        }
        __syncthreads();
        #pragma unroll
        for (int ks = 0; ks < 2; ++ks) {
            bf16x8 af[4], bfr[4];
            #pragma unroll
            for (int mi = 0; mi < 4; ++mi)
                af[mi] = *reinterpret_cast<const bf16x8*>(&As[(64 * wr + 16 * mi + lo) * 64 + 32 * ks + 8 * hi]);
            #pragma unroll
            for (int ni = 0; ni < 4; ++ni)
                bfr[ni] = *reinterpret_cast<const bf16x8*>(&Bs[(64 * wc + 16 * ni + lo) * 64 + 32 * ks + 8 * hi]);
            #pragma unroll
            for (int mi = 0; mi < 4; ++mi)
                #pragma unroll
                for (int ni = 0; ni < 4; ++ni)
                    acc[mi][ni] = MFMA(af[mi], bfr[ni], acc[mi][ni]);
        }
        __syncthreads();
    }

    #pragma unroll
    for (int ni = 0; ni < 4; ++ni) {
        const int col = colBase + 64 * wc + 16 * ni + lo;
        const float bcol = bias[col];
        const int h = col >> 6, d = col & 63;
        #pragma unroll
        for (int mi = 0; mi < 4; ++mi)
            #pragma unroll
            for (int r = 0; r < 4; ++r) {
                const int m = rowBase + 64 * wr + 16 * mi + 4 * hi + r;
                const int b = m >> 11, s = m & (kSEQ - 1);
                const ushortT val = f2bf((acc[mi][ni][r] + bcol) * scale);
                if (z == 2)  // V transposed: [B,H,D,S]
                    out[(((size_t)b * kNH + h) * kHD + d) * kSEQ + s] = val;
                else         // Q,K: [B,H,S,D]
                    out[(((size_t)b * kNH + h) * kSEQ + s) * kHD + d] = val;
            }
    }
}

// ---------------------------------------------------------------------------
// Output GEMM: attnb[4096][1024] bf16 @ Wo (as Wt) + bo -> fp32 d_out.
// ---------------------------------------------------------------------------
__global__ __launch_bounds__(256) void out_mfma_gemm(
    const ushortT* __restrict__ A, const ushortT* __restrict__ Bt,
    const float* __restrict__ bias, float* __restrict__ out) {
    __shared__ ushortT As[128 * 64];
    __shared__ ushortT Bs[128 * 64];

    const int tid = threadIdx.x, wid = tid >> 6, lane = tid & 63;
    const int hi = lane >> 4, lo = lane & 15;
    const int rowBase = blockIdx.y * 128, colBase = blockIdx.x * 128;
    const int wr = wid >> 1, wc = wid & 1;

    const f32x4 z4 = {0.f, 0.f, 0.f, 0.f};
    f32x4 acc[4][4];
    #pragma unroll
    for (int mi = 0; mi < 4; ++mi)
        #pragma unroll
        for (int ni = 0; ni < 4; ++ni) acc[mi][ni] = z4;

    for (int k0 = 0; k0 < kHID; k0 += 64) {
        #pragma unroll
        for (int i = 0; i < 4; ++i) {
            const int chunk = wid * 4 + i;
            const int row = chunk * 8 + (lane >> 3);
            const int c8 = (lane & 7) * 8;
            gload_lds16(&A [(size_t)(rowBase + row) * kHID + k0 + c8], &As[chunk * 512]);
            gload_lds16(&Bt[(size_t)(colBase + row) * kHID + k0 + c8], &Bs[chunk * 512]);
        }
        __syncthreads();
        #pragma unroll
        for (int ks = 0; ks < 2; ++ks) {
            bf16x8 af[4], bfr[4];
            #pragma unroll
            for (int mi = 0; mi < 4; ++mi)
                af[mi] = *reinterpret_cast<const bf16x8*>(&As[(64 * wr + 16 * mi + lo) * 64 + 32 * ks + 8 * hi]);
            #pragma unroll
            for (int ni = 0; ni < 4; ++ni)
                bfr[ni] = *reinterpret_cast<const bf16x8*>(&Bs[(64 * wc + 16 * ni + lo) * 64 + 32 * ks + 8 * hi]);
            #pragma unroll
            for (int mi = 0; mi < 4; ++mi)
                #pragma unroll
                for (int ni = 0; ni < 4; ++ni)
                    acc[mi][ni] = MFMA(af[mi], bfr[ni], acc[mi][ni]);
        }
        __syncthreads();
    }

    #pragma unroll
    for (int ni = 0; ni < 4; ++ni) {
        const int col = colBase + 64 * wc + 16 * ni + lo;
        const float bcol = bias[col];
        #pragma unroll
        for (int mi = 0; mi < 4; ++mi)
            #pragma unroll
            for (int r = 0; r < 4; ++r) {
                const int m = rowBase + 64 * wr + 16 * mi + 4 * hi + r;
                out[(size_t)m * kHID + col] = acc[mi][ni][r] + bcol;
            }
    }
}

// ---------------------------------------------------------------------------
// MFMA flash attention v3. Block = (b, h, 64-row Q tile), 4 waves x 16 q-rows.
// Grid 1024 -> 4 blocks/CU (LDS 40KB). K and V^T double-buffered in LDS via
// global_load_lds w=16 with PRE-SWIZZLED SOURCE (linear dest + XOR-swz read).
// Softmax in log2 domain (Q pre-scaled by 1/8*log2e): raw exp2f, defer-max
// (THR=8 -> P<=256), per-lane partial row-sum reduced once in epilogue.
// ---------------------------------------------------------------------------
__global__ __launch_bounds__(256, 4) void flash_mfma_kernel(
    const ushortT* __restrict__ Qb, const ushortT* __restrict__ Kb,
    const ushortT* __restrict__ Vtg, ushortT* __restrict__ Ob) {
    __shared__ ushortT Ks[2][64 * 64];
    __shared__ ushortT Vs[2][64 * 64];
    __shared__ ushortT Ps[4][16 * 64];

    const int tid = threadIdx.x, wid = tid >> 6, lane = tid & 63;
    const int hi = lane >> 4, lo = lane & 15;
    const int q0 = blockIdx.x * 64;
    const size_t headBase = ((size_t)blockIdx.z * kNH + blockIdx.y) * (size_t)(kSEQ * kHD);
    const ushortT* Kg = Kb + headBase;    // [kv][64]
    const ushortT* Vg = Vtg + headBase;   // [d][2048] (pre-transposed)

    // Q fragments: wave's 16 rows, A-frag row = lo, k = 32c + 8hi + e
    bf16x8 qf[2];
    #pragma unroll
    for (int c = 0; c < 2; ++c)
        qf[c] = *reinterpret_cast<const bf16x8*>(
            &Qb[headBase + (size_t)(q0 + 16 * wid + lo) * kHD + 32 * c + 8 * hi]);

    const f32x4 z4 = {0.f, 0.f, 0.f, 0.f};
    f32x4 acc[4] = {z4, z4, z4, z4};
    float m_[4] = {-INFINITY, -INFINITY, -INFINITY, -INFINITY};
    float l_[4] = {0.f, 0.f, 0.f, 0.f};

    const int r8 = lane >> 3, jc = lane & 7;  // staging: row-within-8, 16B chunk

    // Stage one 64-wide kv tile of K and V^T. Linear LDS dest (gload_lds) with
    // source column pre-XOR'd so the standard ((row&7)<<3) read swizzle applies.
    auto STAGE = [&](int buf, int kv0) {
        #pragma unroll
        for (int i = 0; i < 2; ++i) {
            const int rowBase = (i * 4 + wid) * 8;     // wave-uniform
            const int row = rowBase + r8;              // row&7 == r8
            gload_lds16(&Kg[(size_t)(kv0 + row) * kHD + 8 * (jc ^ r8)], &Ks[buf][rowBase * 64]);
            gload_lds16(&Vg[(size_t)row * kSEQ + kv0 + 8 * (jc ^ r8)], &Vs[buf][rowBase * 64]);
        }
    };

    STAGE(0, 0);
    __syncthreads();   // compiler drains vmcnt(0) before barrier
    int cur = 0;

    for (int t = 0; t < kSEQ / 64; ++t) {
        if (t + 1 < kSEQ / 64) STAGE(cur ^ 1, (t + 1) * 64);   // async prefetch

        // ---- QK^T (8 MFMA): sc[f] reg r = S[4hi+r][16f+lo] in log2 domain ----
        f32x4 sc[4];
        #pragma unroll
        for (int f = 0; f < 4; ++f) {
            const int krow = 16 * f + lo;
            const int swz = (krow & 7) << 3;
            const bf16x8 kf0 = *reinterpret_cast<const bf16x8*>(
                &Ks[cur][krow * 64 + ((8 * hi) ^ swz)]);
            const bf16x8 kf1 = *reinterpret_cast<const bf16x8*>(
                &Ks[cur][krow * 64 + ((32 + 8 * hi) ^ swz)]);
            f32x4 s = z4;
            s = MFMA(qf[0], kf0, s);
            s = MFMA(qf[1], kf1, s);
            sc[f] = s;
        }

        // ---- online softmax: defer-max, per-lane partial sum ----
        #pragma unroll
        for (int r = 0; r < 4; ++r) {
            const float v0 = sc[0][r], v1 = sc[1][r], v2 = sc[2][r], v3 = sc[3][r];
            float rm = fmaxf(fmaxf(v0, v1), fmaxf(v2, v3));
            #pragma unroll
            for (int msk = 1; msk < 16; msk <<= 1) rm = fmaxf(rm, __shfl_xor(rm, msk));
            if (rm > m_[r] + 8.0f) {           // rescale only on real max growth
                const float fac = exp2f(m_[r] - rm);
                m_[r] = rm;
                l_[r] *= fac;
                #pragma unroll
                for (int n = 0; n < 4; ++n) acc[n][r] *= fac;
            }
            const float p0 = exp2f(v0 - m_[r]), p1 = exp2f(v1 - m_[r]);
            const float p2 = exp2f(v2 - m_[r]), p3 = exp2f(v3 - m_[r]);
            l_[r] += p0 + p1 + p2 + p3;        // per-lane partial; reduce at end
            const int prow = 4 * hi + r;
            const int swz = (prow >> 1) << 3;  // store-side conflict-free swizzle
            ushortT* pb = &Ps[wid][prow * 64];
            pb[(lo +  0) ^ swz] = f2bf(p0);
            pb[(lo + 16) ^ swz] = f2bf(p1);
            pb[(lo + 32) ^ swz] = f2bf(p2);
            pb[(lo + 48) ^ swz] = f2bf(p3);
        }

        // ---- PV (8 MFMA): acc[n] += P[16 rows][kv-chunk] x V[kv-chunk][16n..] ----
        #pragma unroll
        for (int c = 0; c < 2; ++c) {
            const bf16x8 pa = *reinterpret_cast<const bf16x8*>(
                &Ps[wid][lo * 64 + ((32 * c + 8 * hi) ^ ((lo >> 1) << 3))]);
            #pragma unroll
            for (int n = 0; n < 4; ++n) {
                const int vrow = 16 * n + lo;
                const bf16x8 vf = *reinterpret_cast<const bf16x8*>(
                    &Vs[cur][vrow * 64 + ((32 * c + 8 * hi) ^ ((vrow & 7) << 3))]);
                acc[n] = MFMA(pa, vf, acc[n]);
            }
        }
        __syncthreads();   // drains prefetch vmcnt + guards buffer swap
        cur ^= 1;
    }

    // ---- epilogue: reduce row sums once, normalize, write bf16 [B,S,HID] ----
    #pragma unroll
    for (int r = 0; r < 4; ++r) {
        float ls = l_[r];
        #pragma unroll
        for (int msk = 1; msk < 16; msk <<= 1) ls += __shfl_xor(ls, msk);
        const float inv = 1.0f / ls;
        const int s = q0 + 16 * wid + 4 * hi + r;
        const size_t base = ((size_t)blockIdx.z * kSEQ + s) * kHID + (size_t)blockIdx.y * kHD;
        #pragma unroll
        for (int n = 0; n < 4; ++n)
            Ob[base + 16 * n + lo] = f2bf(acc[n][r] * inv);
    }
}

}  // namespace

extern "C" void kernel_launch(void* const* d_in, const int* in_sizes, int n_in,
                              void* d_out, int out_size, void* d_ws, size_t ws_size,
                              hipStream_t stream) {
    (void)in_sizes; (void)n_in; (void)out_size;
    const float* x  = (const float*)d_in[0];
    const float* Wq = (const float*)d_in[1];
    const float* bq = (const float*)d_in[2];
    const float* Wk = (const float*)d_in[3];
    const float* bk = (const float*)d_in[4];
    const float* Wv = (const float*)d_in[5];
    const float* bv = (const float*)d_in[6];
    const float* Wo = (const float*)d_in[7];
    const float* bo = (const float*)d_in[8];

    constexpr size_t kXE = (size_t)2 * kSEQ * kHID;   // 4 Mi elems
    constexpr size_t kWE = (size_t)kHID * kHID;       // 1 Mi elems
    const size_t needed = (kXE + 4 * kWE + 3 * kXE + kXE) * sizeof(ushortT);
    if (ws_size < needed) return;

    ushortT* xb    = (ushortT*)d_ws;
    ushortT* WtAll = xb + kXE;
    ushortT* qkvb  = WtAll + 4 * kWE;
    ushortT* attnb = qkvb + 3 * kXE;

    const ushortT* qb  = qkvb;            // [B,H,S,D], pre-scaled
    const ushortT* kb  = qkvb + kXE;      // [B,H,S,D]
    const ushortT* vtb = qkvb + 2 * kXE;  // [B,H,D,S]  (transposed)

    cvtx_kernel<<<dim3((unsigned)(kXE / (256 * 4))), 256, 0, stream>>>(x, xb);
    transw_kernel<<<dim3(16, 16, 4), 256, 0, stream>>>(Wq, Wk, Wv, Wo, WtAll);

    qkv_mfma_gemm<<<dim3(8, 32, 3), 256, 0, stream>>>(xb, WtAll, bq, bk, bv, qkvb);

    flash_mfma_kernel<<<dim3(kSEQ / 64, kNH, 2), 256, 0, stream>>>(qb, kb, vtb, attnb);

    out_mfma_gemm<<<dim3(8, 32), 256, 0, stream>>>(attnb, WtAll + 3 * kWE, bo, (float*)d_out);
}

// Round 4
// 171.713 us; speedup vs baseline: 5.6472x; 1.1773x over previous
//
#include <hip/hip_runtime.h>
#include <math.h>

// bf16-MFMA MHA v4: swapped-QK^T flash attention (lane-local softmax + in-register
// P->PV fragment build via v_cvt_pk_bf16_f32; no P LDS buffer).
// MFMA 16x16x32 bf16 layouts (HW-verified, learn_hip m89/m92):
//   A frag: lane holds A[l&15][8*(l>>4)+e], e=0..7 (k-contiguous bf16x8)
//   B frag: lane holds B[8*(l>>4)+e][l&15]
//   C/D:    lane reg r -> C[(l>>4)*4 + r][l&15]
// Flash trick: S^T = mfma(K,Q) with K-row permutation kappa(f,i)=8(i>>2)+(i&3)+4(f&1)+32(f>>1)
// => lane (lo,hi) holds scores for q=lo, kv = 8hi+r+4(f&1)+32(f>>1); packing p[f] pairs
// yields exactly the PV A-fragment (kv = 32c+8hi+e) with zero cross-lane traffic.

namespace {

constexpr int kHID = 1024;
constexpr int kNH  = 16;
constexpr int kHD  = 64;
constexpr int kSEQ = 2048;

// 1/sqrt(64) * log2(e): scores in log2 domain -> exp2f softmax.
constexpr float kQScale = 0.125f * 1.4426950408889634f;

typedef unsigned short ushortT;
typedef __attribute__((ext_vector_type(8))) short   bf16x8;
typedef __attribute__((ext_vector_type(4))) float   f32x4;
typedef __attribute__((ext_vector_type(4))) unsigned short u16x4;

#define MFMA(a, b, c) __builtin_amdgcn_mfma_f32_16x16x32_bf16((a), (b), (c), 0, 0, 0)

typedef const __attribute__((address_space(1))) void GVoid;
typedef __attribute__((address_space(3))) void SVoid;

__device__ __forceinline__ void gload_lds16(const ushortT* g, ushortT* l) {
    __builtin_amdgcn_global_load_lds((GVoid*)g, (SVoid*)l, 16, 0, 0);
}

__device__ __forceinline__ ushortT f2bf(float f) {
    unsigned u = __builtin_bit_cast(unsigned, f);
    u += 0x7fffu + ((u >> 16) & 1u);
    return (ushortT)(u >> 16);
}

__device__ __forceinline__ unsigned cvt_pk_bf16(float a, float b) {
    unsigned r;
    asm("v_cvt_pk_bf16_f32 %0, %1, %2" : "=v"(r) : "v"(a), "v"(b));
    return r;  // low half = bf16(a), high half = bf16(b)
}

__device__ __forceinline__ float4 ld4f(const float* p) { return *reinterpret_cast<const float4*>(p); }

// ---------------------------------------------------------------------------
// x fp32 -> bf16
// ---------------------------------------------------------------------------
__global__ __launch_bounds__(256) void cvtx_kernel(const float* __restrict__ x,
                                                   ushortT* __restrict__ xb) {
    const size_t i = ((size_t)blockIdx.x * 256 + threadIdx.x) * 4;
    const float4 f = ld4f(&x[i]);
    u16x4 o = { f2bf(f.x), f2bf(f.y), f2bf(f.z), f2bf(f.w) };
    *reinterpret_cast<u16x4*>(&xb[i]) = o;
}

// ---------------------------------------------------------------------------
// W[k][n] fp32 -> Wt[n][k] bf16, 64x64 tiles via LDS. z selects matrix.
// ---------------------------------------------------------------------------
__global__ __launch_bounds__(256) void transw_kernel(
    const float* __restrict__ W0, const float* __restrict__ W1,
    const float* __restrict__ W2, const float* __restrict__ W3,
    ushortT* __restrict__ WtAll) {
    __shared__ ushortT T[64 * 72];
    const float* W = (blockIdx.z == 0) ? W0 : (blockIdx.z == 1) ? W1 : (blockIdx.z == 2) ? W2 : W3;
    ushortT* Wt = WtAll + (size_t)blockIdx.z * kHID * kHID;
    const int kb = blockIdx.y * 64, nb = blockIdx.x * 64;
    const int tid = threadIdx.x;
    {
        const int kr = tid >> 2, nc = (tid & 3) * 16;
        #pragma unroll
        for (int i = 0; i < 16; i += 4) {
            const float4 f = ld4f(&W[(size_t)(kb + kr) * kHID + nb + nc + i]);
            T[kr * 72 + nc + i + 0] = f2bf(f.x);
            T[kr * 72 + nc + i + 1] = f2bf(f.y);
            T[kr * 72 + nc + i + 2] = f2bf(f.z);
            T[kr * 72 + nc + i + 3] = f2bf(f.w);
        }
    }
    __syncthreads();
    {
        const int nr = tid >> 2, kc = (tid & 3) * 16;
        ushortT tmp[16];
        #pragma unroll
        for (int i = 0; i < 16; ++i) tmp[i] = T[(kc + i) * 72 + nr];
        *reinterpret_cast<bf16x8*>(&Wt[(size_t)(nb + nr) * kHID + kb + kc]) =
            *reinterpret_cast<bf16x8*>(&tmp[0]);
        *reinterpret_cast<bf16x8*>(&Wt[(size_t)(nb + nr) * kHID + kb + kc + 8]) =
            *reinterpret_cast<bf16x8*>(&tmp[8]);
    }
}

// ---------------------------------------------------------------------------
// QKV GEMM: xb[4096][1024] @ W (as Wt[n][k]) + bias -> bf16.
// Q (z==0): [B,H,S,D] scaled by kQScale.  K (z==1): [B,H,S,D].
// V (z==2): TRANSPOSED [B,H,D,S] so flash stages V^T with plain vector copies.
// ---------------------------------------------------------------------------
__global__ __launch_bounds__(256) void qkv_mfma_gemm(
    const ushortT* __restrict__ A, const ushortT* __restrict__ WtAll,
    const float* __restrict__ bq, const float* __restrict__ bk, const float* __restrict__ bv,
    ushortT* __restrict__ qkvb) {
    __shared__ ushortT As[128 * 64];
    __shared__ ushortT Bs[128 * 64];

    const int z = blockIdx.z;
    const ushortT* Bt = WtAll + (size_t)z * kHID * kHID;
    const float* bias = (z == 0) ? bq : (z == 1) ? bk : bv;
    ushortT* out = qkvb + (size_t)z * 2 * kNH * kSEQ * kHD;
    const float scale = (z == 0) ? kQScale : 1.0f;

    const int tid = threadIdx.x, wid = tid >> 6, lane = tid & 63;
    const int hi = lane >> 4, lo = lane & 15;
    const int rowBase = blockIdx.y * 128, colBase = blockIdx.x * 128;
    const int wr = wid >> 1, wc = wid & 1;

    const f32x4 z4 = {0.f, 0.f, 0.f, 0.f};
    f32x4 acc[4][4];
    #pragma unroll
    for (int mi = 0; mi < 4; ++mi)
        #pragma unroll
        for (int ni = 0; ni < 4; ++ni) acc[mi][ni] = z4;

    for (int k0 = 0; k0 < kHID; k0 += 64) {
        #pragma unroll
        for (int i = 0; i < 4; ++i) {
            const int chunk = wid * 4 + i;                 // wave-uniform
            const int row = chunk * 8 + (lane >> 3);
            const int c8 = (lane & 7) * 8;
            gload_lds16(&A [(size_t)(rowBase + row) * kHID + k0 + c8], &As[chunk * 512]);
            gload_lds16(&Bt[(size_t)(colBase + row) * kHID + k0 + c8], &Bs[chunk * 512]);
        }
        __syncthreads();
        #pragma unroll
        for (int ks = 0; ks < 2; ++ks) {
            bf16x8 af[4], bfr[4];
            #pragma unroll
            for (int mi = 0; mi < 4; ++mi)
                af[mi] = *reinterpret_cast<const bf16x8*>(&As[(64 * wr + 16 * mi + lo) * 64 + 32 * ks + 8 * hi]);
            #pragma unroll
            for (int ni = 0; ni < 4; ++ni)
                bfr[ni] = *reinterpret_cast<const bf16x8*>(&Bs[(64 * wc + 16 * ni + lo) * 64 + 32 * ks + 8 * hi]);
            #pragma unroll
            for (int mi = 0; mi < 4; ++mi)
                #pragma unroll
                for (int ni = 0; ni < 4; ++ni)
                    acc[mi][ni] = MFMA(af[mi], bfr[ni], acc[mi][ni]);
        }
        __syncthreads();
    }

    #pragma unroll
    for (int ni = 0; ni < 4; ++ni) {
        const int col = colBase + 64 * wc + 16 * ni + lo;
        const float bcol = bias[col];
        const int h = col >> 6, d = col & 63;
        #pragma unroll
        for (int mi = 0; mi < 4; ++mi)
            #pragma unroll
            for (int r = 0; r < 4; ++r) {
                const int m = rowBase + 64 * wr + 16 * mi + 4 * hi + r;
                const int b = m >> 11, s = m & (kSEQ - 1);
                const ushortT val = f2bf((acc[mi][ni][r] + bcol) * scale);
                if (z == 2)  // V transposed: [B,H,D,S]
                    out[(((size_t)b * kNH + h) * kHD + d) * kSEQ + s] = val;
                else         // Q,K: [B,H,S,D]
                    out[(((size_t)b * kNH + h) * kSEQ + s) * kHD + d] = val;
            }
    }
}

// ---------------------------------------------------------------------------
// Output GEMM: attnb[4096][1024] bf16 @ Wo (as Wt) + bo -> fp32 d_out.
// ---------------------------------------------------------------------------
__global__ __launch_bounds__(256) void out_mfma_gemm(
    const ushortT* __restrict__ A, const ushortT* __restrict__ Bt,
    const float* __restrict__ bias, float* __restrict__ out) {
    __shared__ ushortT As[128 * 64];
    __shared__ ushortT Bs[128 * 64];

    const int tid = threadIdx.x, wid = tid >> 6, lane = tid & 63;
    const int hi = lane >> 4, lo = lane & 15;
    const int rowBase = blockIdx.y * 128, colBase = blockIdx.x * 128;
    const int wr = wid >> 1, wc = wid & 1;

    const f32x4 z4 = {0.f, 0.f, 0.f, 0.f};
    f32x4 acc[4][4];
    #pragma unroll
    for (int mi = 0; mi < 4; ++mi)
        #pragma unroll
        for (int ni = 0; ni < 4; ++ni) acc[mi][ni] = z4;

    for (int k0 = 0; k0 < kHID; k0 += 64) {
        #pragma unroll
        for (int i = 0; i < 4; ++i) {
            const int chunk = wid * 4 + i;
            const int row = chunk * 8 + (lane >> 3);
            const int c8 = (lane & 7) * 8;
            gload_lds16(&A [(size_t)(rowBase + row) * kHID + k0 + c8], &As[chunk * 512]);
            gload_lds16(&Bt[(size_t)(colBase + row) * kHID + k0 + c8], &Bs[chunk * 512]);
        }
        __syncthreads();
        #pragma unroll
        for (int ks = 0; ks < 2; ++ks) {
            bf16x8 af[4], bfr[4];
            #pragma unroll
            for (int mi = 0; mi < 4; ++mi)
                af[mi] = *reinterpret_cast<const bf16x8*>(&As[(64 * wr + 16 * mi + lo) * 64 + 32 * ks + 8 * hi]);
            #pragma unroll
            for (int ni = 0; ni < 4; ++ni)
                bfr[ni] = *reinterpret_cast<const bf16x8*>(&Bs[(64 * wc + 16 * ni + lo) * 64 + 32 * ks + 8 * hi]);
            #pragma unroll
            for (int mi = 0; mi < 4; ++mi)
                #pragma unroll
                for (int ni = 0; ni < 4; ++ni)
                    acc[mi][ni] = MFMA(af[mi], bfr[ni], acc[mi][ni]);
        }
        __syncthreads();
    }

    #pragma unroll
    for (int ni = 0; ni < 4; ++ni) {
        const int col = colBase + 64 * wc + 16 * ni + lo;
        const float bcol = bias[col];
        #pragma unroll
        for (int mi = 0; mi < 4; ++mi)
            #pragma unroll
            for (int r = 0; r < 4; ++r) {
                const int m = rowBase + 64 * wr + 16 * mi + 4 * hi + r;
                out[(size_t)m * kHID + col] = acc[mi][ni][r] + bcol;
            }
    }
}

// ---------------------------------------------------------------------------
// MFMA flash attention v4 (swapped QK^T). Block = (b,h,64 q-rows), 4 waves x 16.
// K and V^T double-buffered in LDS via global_load_lds w=16 with pre-swizzled
// source; swizzle s(row) = (row&3)|(((row>>3)&1)<<2) (bank-uniform under the
// permuted K-fragment row set AND the V read). Softmax fully lane-local.
// ---------------------------------------------------------------------------
__global__ __launch_bounds__(256, 4) void flash_mfma_kernel(
    const ushortT* __restrict__ Qb, const ushortT* __restrict__ Kb,
    const ushortT* __restrict__ Vtg, ushortT* __restrict__ Ob) {
    __shared__ ushortT Ks[2][64 * 64];
    __shared__ ushortT Vs[2][64 * 64];

    const int tid = threadIdx.x, wid = tid >> 6, lane = tid & 63;
    const int hi = lane >> 4, lo = lane & 15;
    const int q0 = blockIdx.x * 64;
    const size_t headBase = ((size_t)blockIdx.z * kNH + blockIdx.y) * (size_t)(kSEQ * kHD);
    const ushortT* Kg = Kb + headBase;    // [kv][64]
    const ushortT* Vg = Vtg + headBase;   // [d][2048] (pre-transposed)

    // Q fragments (B-operand of swapped QK^T): lane holds Q[q=lo][d=32c+8hi+e]
    bf16x8 qf[2];
    #pragma unroll
    for (int c = 0; c < 2; ++c)
        qf[c] = *reinterpret_cast<const bf16x8*>(
            &Qb[headBase + (size_t)(q0 + 16 * wid + lo) * kHD + 32 * c + 8 * hi]);

    const f32x4 z4 = {0.f, 0.f, 0.f, 0.f};
    f32x4 acc[4] = {z4, z4, z4, z4};
    float m_ = -INFINITY;   // running row-max of q=lo (log2 domain)
    float l_ = 0.f;         // per-lane partial row-sum of q=lo

    const int r8 = lane >> 3, jc = lane & 7;  // staging: row-within-8, 16B chunk

    // K-fragment addressing (row-permuted): kappa = 8*(lo>>2)+(lo&3)+4*(f&1)+32*(f>>1)
    const int kap0 = 8 * (lo >> 2) + (lo & 3);
    const int sk = (lo & 3) | (((lo >> 2) & 1) << 2);        // s(kappa), f-invariant
    const int kx0 = (8 * hi) ^ (sk << 3);                     // d-chunk m=0
    const int kx1 = (32 + 8 * hi) ^ (sk << 3);                // d-chunk m=1
    const int sv = (lo & 3) | (((lo >> 3) & 1) << 2);         // s(vrow), n-invariant

    // Stage one 64-wide kv tile of K and V^T: linear LDS dest, source column
    // pre-XOR'd by s(row) so swizzled reads see G[row][x] at LDS[row][x^(s<<3)].
    auto STAGE = [&](int buf, int kv0) {
        #pragma unroll
        for (int i = 0; i < 2; ++i) {
            const int rowBase = (i * 4 + wid) * 8;            // wave-uniform
            const int row = rowBase + r8;
            const int s8 = (r8 & 3) | ((wid & 1) << 2);       // s(row)
            gload_lds16(&Kg[(size_t)(kv0 + row) * kHD + 8 * (jc ^ s8)], &Ks[buf][rowBase * 64]);
            gload_lds16(&Vg[(size_t)row * kSEQ + kv0 + 8 * (jc ^ s8)], &Vs[buf][rowBase * 64]);
        }
    };

    STAGE(0, 0);
    __syncthreads();
    int cur = 0;

    for (int t = 0; t < kSEQ / 64; ++t) {
        if (t + 1 < kSEQ / 64) STAGE(cur ^ 1, (t + 1) * 64);   // async prefetch

        // ---- swapped QK^T (8 MFMA): sc[f] reg r = S[q=lo][kv=8hi+r+4(f&1)+32(f>>1)] ----
        f32x4 sc[4];
        #pragma unroll
        for (int f = 0; f < 4; ++f) {
            const int kap = kap0 + 4 * (f & 1) + 32 * (f >> 1);
            const bf16x8 kf0 = *reinterpret_cast<const bf16x8*>(&Ks[cur][kap * 64 + kx0]);
            const bf16x8 kf1 = *reinterpret_cast<const bf16x8*>(&Ks[cur][kap * 64 + kx1]);
            f32x4 s = z4;
            s = MFMA(kf0, qf[0], s);
            s = MFMA(kf1, qf[1], s);
            sc[f] = s;
        }

        // ---- lane-local softmax (q = lo) ----
        float rm = sc[0][0];
        #pragma unroll
        for (int f = 0; f < 4; ++f)
            #pragma unroll
            for (int r = 0; r < 4; ++r) rm = fmaxf(rm, sc[f][r]);
        rm = fmaxf(rm, __shfl_xor(rm, 16));
        rm = fmaxf(rm, __shfl_xor(rm, 32));

        const bool grow = rm > m_ + 8.0f;                     // defer-max (log2 THR=8)
        if (__any(grow)) {
            const float nm = grow ? rm : m_;
            const float fac = exp2f(m_ - nm);
            m_ = nm;
            l_ *= fac;
            float facO[4];
            #pragma unroll
            for (int r = 0; r < 4; ++r) facO[r] = __shfl(fac, 4 * hi + r);
            #pragma unroll
            for (int n = 0; n < 4; ++n)
                #pragma unroll
                for (int r = 0; r < 4; ++r) acc[n][r] *= facO[r];
        }

        float p[4][4];
        float ps = 0.f;
        #pragma unroll
        for (int f = 0; f < 4; ++f)
            #pragma unroll
            for (int r = 0; r < 4; ++r) {
                p[f][r] = exp2f(sc[f][r] - m_);
                ps += p[f][r];
            }
        l_ += ps;

        // ---- build PV A-fragments in-register: af_c u32 j holds kv pair 32c+8hi+2j ----
        union { unsigned u[4]; bf16x8 v; } pa0, pa1;
        pa0.u[0] = cvt_pk_bf16(p[0][0], p[0][1]);
        pa0.u[1] = cvt_pk_bf16(p[0][2], p[0][3]);
        pa0.u[2] = cvt_pk_bf16(p[1][0], p[1][1]);
        pa0.u[3] = cvt_pk_bf16(p[1][2], p[1][3]);
        pa1.u[0] = cvt_pk_bf16(p[2][0], p[2][1]);
        pa1.u[1] = cvt_pk_bf16(p[2][2], p[2][3]);
        pa1.u[2] = cvt_pk_bf16(p[3][0], p[3][1]);
        pa1.u[3] = cvt_pk_bf16(p[3][2], p[3][3]);

        // ---- PV (8 MFMA): acc[n] += P[q][kv-chunk] x V[kv-chunk][16n+lo] ----
        #pragma unroll
        for (int n = 0; n < 4; ++n) {
            const int vrow = 16 * n + lo;
            const bf16x8 vf0 = *reinterpret_cast<const bf16x8*>(
                &Vs[cur][vrow * 64 + ((8 * hi) ^ (sv << 3))]);
            const bf16x8 vf1 = *reinterpret_cast<const bf16x8*>(
                &Vs[cur][vrow * 64 + ((32 + 8 * hi) ^ (sv << 3))]);
            acc[n] = MFMA(pa0.v, vf0, acc[n]);
            acc[n] = MFMA(pa1.v, vf1, acc[n]);
        }
        __syncthreads();   // drains prefetch vmcnt + guards buffer swap
        cur ^= 1;
    }

    // ---- epilogue: finish row sums, route to acc's q-rows, write bf16 [B,S,HID] ----
    float ls = l_;
    ls += __shfl_xor(ls, 16);
    ls += __shfl_xor(ls, 32);
    #pragma unroll
    for (int r = 0; r < 4; ++r) {
        const float inv = 1.0f / __shfl(ls, 4 * hi + r);
        const int s = q0 + 16 * wid + 4 * hi + r;
        const size_t base = ((size_t)blockIdx.z * kSEQ + s) * kHID + (size_t)blockIdx.y * kHD;
        #pragma unroll
        for (int n = 0; n < 4; ++n)
            Ob[base + 16 * n + lo] = f2bf(acc[n][r] * inv);
    }
}

}  // namespace

extern "C" void kernel_launch(void* const* d_in, const int* in_sizes, int n_in,
                              void* d_out, int out_size, void* d_ws, size_t ws_size,
                              hipStream_t stream) {
    (void)in_sizes; (void)n_in; (void)out_size;
    const float* x  = (const float*)d_in[0];
    const float* Wq = (const float*)d_in[1];
    const float* bq = (const float*)d_in[2];
    const float* Wk = (const float*)d_in[3];
    const float* bk = (const float*)d_in[4];
    const float* Wv = (const float*)d_in[5];
    const float* bv = (const float*)d_in[6];
    const float* Wo = (const float*)d_in[7];
    const float* bo = (const float*)d_in[8];

    constexpr size_t kXE = (size_t)2 * kSEQ * kHID;   // 4 Mi elems
    constexpr size_t kWE = (size_t)kHID * kHID;       // 1 Mi elems
    const size_t needed = (kXE + 4 * kWE + 3 * kXE + kXE) * sizeof(ushortT);
    if (ws_size < needed) return;

    ushortT* xb    = (ushortT*)d_ws;
    ushortT* WtAll = xb + kXE;
    ushortT* qkvb  = WtAll + 4 * kWE;
    ushortT* attnb = qkvb + 3 * kXE;

    const ushortT* qb  = qkvb;            // [B,H,S,D], pre-scaled by 0.125*log2e
    const ushortT* kb  = qkvb + kXE;      // [B,H,S,D]
    const ushortT* vtb = qkvb + 2 * kXE;  // [B,H,D,S]  (transposed)

    cvtx_kernel<<<dim3((unsigned)(kXE / (256 * 4))), 256, 0, stream>>>(x, xb);
    transw_kernel<<<dim3(16, 16, 4), 256, 0, stream>>>(Wq, Wk, Wv, Wo, WtAll);

    qkv_mfma_gemm<<<dim3(8, 32, 3), 256, 0, stream>>>(xb, WtAll, bq, bk, bv, qkvb);

    flash_mfma_kernel<<<dim3(kSEQ / 64, kNH, 2), 256, 0, stream>>>(qb, kb, vtb, attnb);

    out_mfma_gemm<<<dim3(8, 32), 256, 0, stream>>>(attnb, WtAll + 3 * kWE, bo, (float*)d_out);
}